// Round 15
// baseline (47.122 us; speedup 1.0000x reference)
//
#include <hip/hip_runtime.h>
#include <math.h>

#define KW_ELEMS 294912   // 3*3*128*256
#define LR_GD 0.01
#define NBLK_RED 64       // partial-reduction blocks

typedef __attribute__((ext_vector_type(8))) short short8;
typedef __attribute__((ext_vector_type(4))) float f32x4;

// ws layout (bytes):
//   0      : double stats_parts[64][2]      (sum, sumsq)   1024 B
//   1024   : int    Gint[15]   (atomic finals)               60 B
//   1088   : double c5[5]      (atomic finals)               40 B
//   1152   : ushort W2[9][4][4][256][8]  (bf16)          589824 B
//   590976 : ushort XE[8][34][34][128]   (bf16, padded, pos-swizzled)
#define WS_SP_OFF    0
#define WS_G_OFF     1024
#define WS_C_OFF     1088
#define WS_WP_OFF    1152
#define WS_XE_OFF    590976
#define XE_CHUNKS    (8 * 34 * 34 * 16)   // 16B chunks

__device__ __forceinline__ unsigned short f2bf(float f) {
    union { float f; unsigned int u; } v; v.f = f;
    unsigned int r = v.u + 0x7fffu + ((v.u >> 16) & 1u);   // RNE
    return (unsigned short)(r >> 16);
}

// lane-parallel read of the 128 stats partials + butterfly reduce.
__device__ __forceinline__ void read_stats(const double* sp, double& sw, double& sw2) {
    int lane = threadIdx.x & 63;
    double a = sp[2 * lane];
    double b = sp[2 * lane + 1];
    #pragma unroll
    for (int off = 32; off > 0; off >>= 1) {
        a += __shfl_xor(a, off, 64);
        b += __shfl_xor(b, off, 64);
    }
    sw = a; sw2 = b;
}

// sign(clip(x+s,0,1)-0.5) == sign((x+s)-0.5) exactly.
__device__ __forceinline__ float xeff_one(float xv, float s0, float s1, float s2,
                                          float be0, float be1, float be2) {
    float v0 = xv + s0, v1 = xv + s1, v2 = xv + s2;
    float g0 = (v0 > 0.5f) ? 1.0f : ((v0 < 0.5f) ? -1.0f : 0.0f);
    float g1 = (v1 > 0.5f) ? 1.0f : ((v1 < 0.5f) ? -1.0f : 0.0f);
    float g2 = (v2 > 0.5f) ? 1.0f : ((v2 < 0.5f) ? -1.0f : 0.0f);
    return be0 * g0 + be1 * g1 + be2 * g2;
}

// ---------------- K1: stats partials (blocks 0-63) + X_eff buffer (64-191) ---
__global__ __launch_bounds__(256) void k_pre(const float* __restrict__ w,
                                             const float* __restrict__ x,
                                             const float* __restrict__ shiftp,
                                             const float* __restrict__ beta,
                                             void* __restrict__ wsv) {
    int tid = threadIdx.x;

    if (blockIdx.x < NBLK_RED) {
        double* sp = (double*)((char*)wsv + WS_SP_OFF);
        int*    gw = (int*)((char*)wsv + WS_G_OFF);
        double* cw = (double*)((char*)wsv + WS_C_OFF);
        __shared__ double s1[256];
        __shared__ double s2[256];

        if (blockIdx.x == 0) {
            if (tid < 15) gw[tid] = 0;
            if (tid >= 32 && tid < 37) cw[tid - 32] = 0.0;
        }

        double a = 0.0, b = 0.0;
        for (int i = blockIdx.x * 256 + tid; i < KW_ELEMS; i += NBLK_RED * 256) {
            double v = (double)w[i];
            a += v; b += v * v;
        }
        s1[tid] = a; s2[tid] = b;
        __syncthreads();
        for (int off = 128; off > 0; off >>= 1) {
            if (tid < off) { s1[tid] += s1[tid + off]; s2[tid] += s2[tid + off]; }
            __syncthreads();
        }
        if (tid == 0) { sp[blockIdx.x * 2] = s1[0]; sp[blockIdx.x * 2 + 1] = s2[0]; }
    } else {
        // X_eff padded buffer: [b][row 0..33][pos 0..33][128] bf16,
        // row=global+1, pos=global+1, borders zero, pos-keyed 16B XOR swizzle.
        unsigned short* xe = (unsigned short*)((char*)wsv + WS_XE_OFF);
        float s0 = shiftp[0], s1v = shiftp[1], s2v = shiftp[2];
        float be0 = beta[0], be1 = beta[1], be2 = beta[2];

        for (int idx = (blockIdx.x - NBLK_RED) * 256 + tid; idx < XE_CHUNKS;
             idx += 128 * 256) {
            int cb  = idx & 15;
            int c2  = idx >> 4;            // (b*34+row)*34 + pos
            int pos = c2 % 34;
            int t   = c2 / 34;
            int row = t % 34;
            int b   = t / 34;
            int g   = row - 1;
            int wp  = pos - 1;
            unsigned short v[8] = {0, 0, 0, 0, 0, 0, 0, 0};
            if (g >= 0 && g < 32 && wp >= 0 && wp < 32) {
                const float* xp = &x[(((b * 32 + g) * 32) + wp) * 128 + cb * 8];
                float4 x0 = *(const float4*)(xp);
                float4 x1 = *(const float4*)(xp + 4);
                float e[8] = {x0.x, x0.y, x0.z, x0.w, x1.x, x1.y, x1.z, x1.w};
                #pragma unroll
                for (int j = 0; j < 8; j++)
                    v[j] = f2bf(xeff_one(e[j], s0, s1v, s2v, be0, be1, be2));
            }
            int dst = c2 * 256 + ((cb * 16) ^ ((pos & 7) << 4));
            *(short8*)((char*)xe + dst) = *(short8*)v;
        }
    }
}

// ---------------- K2: Gram counts + c, atomic finals -------------------------
__global__ __launch_bounds__(256) void k_gc(const float* __restrict__ w,
                                            void* __restrict__ wsv) {
    const double* sp = (const double*)((const char*)wsv + WS_SP_OFF);
    int*    gw = (int*)((char*)wsv + WS_G_OFF);
    double* cw = (double*)((char*)wsv + WS_C_OFF);

    __shared__ int    lg[4][15];
    __shared__ double lc[4][5];

    double sw, sw2;
    read_stats(sp, sw, sw2);
    double mean = sw / (double)KW_ELEMS;
    double var  = sw2 / (double)KW_ELEMS - mean * mean;
    float meanf = (float)mean;
    float sigf  = sqrtf((float)var);

    float sh[5];
    #pragma unroll
    for (int m = 0; m < 5; m++) sh[m] = (-1.0f + 0.5f * (float)m) * sigf;

    int g[15]; double c[5];
    #pragma unroll
    for (int t = 0; t < 15; t++) g[t] = 0;
    #pragma unroll
    for (int i = 0; i < 5; i++) c[i] = 0.0;

    for (int idx = blockIdx.x * 256 + threadIdx.x; idx < KW_ELEMS;
         idx += NBLK_RED * 256) {
        float wf = w[idx];
        float base = wf - meanf;
        int s[5];
        #pragma unroll
        for (int m = 0; m < 5; m++) {
            float arg = base + sh[m];
            s[m] = (arg > 0.0f) ? 1 : ((arg < 0.0f) ? -1 : 0);
        }
        int t = 0;
        #pragma unroll
        for (int i = 0; i < 5; i++) {
            #pragma unroll
            for (int j = i; j < 5; j++) { g[t] += s[i] * s[j]; t++; }
            c[i] += (double)s[i] * (double)wf;
        }
    }
    #pragma unroll
    for (int t = 0; t < 15; t++) {
        int v = g[t];
        for (int off = 32; off > 0; off >>= 1) v += __shfl_down(v, off, 64);
        g[t] = v;
    }
    #pragma unroll
    for (int i = 0; i < 5; i++) {
        double v = c[i];
        for (int off = 32; off > 0; off >>= 1) v += __shfl_down(v, off, 64);
        c[i] = v;
    }
    int wave = threadIdx.x >> 6;
    if ((threadIdx.x & 63) == 0) {
        #pragma unroll
        for (int t = 0; t < 15; t++) lg[wave][t] = g[t];
        #pragma unroll
        for (int i = 0; i < 5; i++) lc[wave][i] = c[i];
    }
    __syncthreads();
    if (threadIdx.x == 0) {
        #pragma unroll
        for (int t = 0; t < 15; t++)
            atomicAdd(&gw[t], lg[0][t] + lg[1][t] + lg[2][t] + lg[3][t]);
        #pragma unroll
        for (int i = 0; i < 5; i++)
            atomicAdd(&cw[i], lc[0][i] + lc[1][i] + lc[2][i] + lc[3][i]);
    }
}

// ---------------- K3: W2 pack + lane-parallel closed-form alpha solve --------
// grid 144 = tap(9) x cin-quarter(4) x cout-quarter(4).
__global__ __launch_bounds__(256) void k_weff(const float* __restrict__ w,
                                              const float* __restrict__ a0f,
                                              void* __restrict__ wsv) {
    const double* sp = (const double*)((const char*)wsv + WS_SP_OFF);
    const int*    gw = (const int*)((const char*)wsv + WS_G_OFF);
    const double* cw = (const double*)((const char*)wsv + WS_C_OFF);
    unsigned short* wpk = (unsigned short*)((char*)wsv + WS_WP_OFF);

    __shared__ double Gd[25], Am[25], Rm[25], Tm[25];
    __shared__ double astar_s[5];
    __shared__ float  alph[5];
    __shared__ float  tile[32][64];

    int tid   = threadIdx.x;
    int tap   = blockIdx.x >> 4;
    int rest  = blockIdx.x & 15;
    int c32   = rest >> 2;          // cin 32-block index
    int cin0  = c32 * 32;
    int cout0 = (rest & 3) * 64;

    // phase A: issue tile loads — in flight during solve
    int i0 = tid, i1 = tid + 256;
    int ci0 = i0 >> 4, f40 = i0 & 15;
    int ci1 = i1 >> 4, f41 = i1 & 15;
    float4 v0 = *(const float4*)(&w[(tap * 128 + cin0 + ci0) * 256 + cout0 + f40 * 4]);
    float4 v1 = *(const float4*)(&w[(tap * 128 + cin0 + ci1) * 256 + cout0 + f41 * 4]);

    double sw, sw2;
    read_stats(sp, sw, sw2);
    double mean = sw / (double)KW_ELEMS;
    double var  = sw2 / (double)KW_ELEMS - mean * mean;
    float meanf = (float)mean;
    float sigf  = sqrtf((float)var);

    // stage G, A=I-LR*G, R=A into LDS (lanes 0-24)
    if (tid < 25) {
        int i = tid / 5, j = tid % 5;
        int ii = (i < j) ? i : j;
        int jj = (i < j) ? j : i;
        int t = 5 * ii - (ii * (ii - 1)) / 2 + (jj - ii);
        double v = (double)gw[t] / (double)KW_ELEMS;
        Gd[tid] = v;
        double a = ((i == j) ? 1.0 : 0.0) - LR_GD * v;
        Am[tid] = a;
        Rm[tid] = a;
    }
    __syncthreads();

    // wave 1, lane 64: Cholesky + triangular solves, concurrent with rounds.
    if (tid == 64) {
        double L[25];
        #pragma unroll
        for (int i = 0; i < 25; i++) L[i] = 0.0;
        #pragma unroll
        for (int i = 0; i < 5; i++) {
            #pragma unroll
            for (int j = 0; j <= i; j++) {
                double s = Gd[i * 5 + j];
                #pragma unroll
                for (int k = 0; k < j; k++) s -= L[i * 5 + k] * L[j * 5 + k];
                if (i == j) L[i * 5 + j] = sqrt(s);
                else        L[i * 5 + j] = s / L[j * 5 + j];
            }
        }
        double y[5], astar[5];
        #pragma unroll
        for (int i = 0; i < 5; i++) {
            double s = cw[i] / (double)KW_ELEMS;
            #pragma unroll
            for (int k = 0; k < i; k++) s -= L[i * 5 + k] * y[k];
            y[i] = s / L[i * 5 + i];
        }
        #pragma unroll
        for (int ii2 = 0; ii2 < 5; ii2++) {
            int i = 4 - ii2;
            double s = y[i];
            #pragma unroll
            for (int k = 0; k < 5; k++) if (k > i) s -= L[k * 5 + i] * astar[k];
            astar[i] = s / L[i * 5 + i];
        }
        #pragma unroll
        for (int i = 0; i < 5; i++) astar_s[i] = astar[i];
    }

    // A^500 rounds (500 = square-and-multiply bits 1,1,1,1,0,1,0,0)
    {
        int i = tid / 5, j = tid % 5;
        const int bits[8] = {1, 1, 1, 1, 0, 1, 0, 0};
        #pragma unroll
        for (int s = 0; s < 8; s++) {
            double tv = 0.0;
            if (tid < 25) {
                #pragma unroll
                for (int k = 0; k < 5; k++) tv += Rm[i * 5 + k] * Rm[k * 5 + j];
                Tm[tid] = tv;
            }
            __syncthreads();
            double rv = tv;
            if (tid < 25) {
                if (bits[s]) {
                    rv = 0.0;
                    #pragma unroll
                    for (int k = 0; k < 5; k++) rv += Tm[i * 5 + k] * Am[k * 5 + j];
                }
                Rm[tid] = rv;
            }
            __syncthreads();
        }
    }

    // alph = astar + R (a0 - astar), lanes 0-4
    if (tid < 5) {
        double s = astar_s[tid];
        #pragma unroll
        for (int j = 0; j < 5; j++)
            s += Rm[tid * 5 + j] * ((double)a0f[j] - astar_s[j]);
        alph[tid] = (float)s;
    }
    __syncthreads();

    float al[5] = {alph[0], alph[1], alph[2], alph[3], alph[4]};

    // phase C: combine + LDS transpose + bf16 pack
    {
        float r[4] = {v0.x, v0.y, v0.z, v0.w};
        #pragma unroll
        for (int j = 0; j < 4; j++) {
            float base = r[j] - meanf;
            float acc = 0.0f;
            #pragma unroll
            for (int m = 0; m < 5; m++) {
                float arg = base + (-1.0f + 0.5f * (float)m) * sigf;
                float s = (arg > 0.0f) ? 1.0f : ((arg < 0.0f) ? -1.0f : 0.0f);
                acc += al[m] * s;
            }
            tile[ci0][f40 * 4 + j] = acc;
        }
        float r1[4] = {v1.x, v1.y, v1.z, v1.w};
        #pragma unroll
        for (int j = 0; j < 4; j++) {
            float base = r1[j] - meanf;
            float acc = 0.0f;
            #pragma unroll
            for (int m = 0; m < 5; m++) {
                float arg = base + (-1.0f + 0.5f * (float)m) * sigf;
                float s = (arg > 0.0f) ? 1.0f : ((arg < 0.0f) ? -1.0f : 0.0f);
                acc += al[m] * s;
            }
            tile[ci1][f41 * 4 + j] = acc;
        }
    }
    __syncthreads();

    int cc  = tid & 63;
    int kg  = tid >> 6;          // 8-cin chunk within the 32-block
    unsigned short ob[8];
    #pragma unroll
    for (int k = 0; k < 8; k++) ob[k] = f2bf(tile[kg * 8 + k][cc]);
    unsigned short* dst = wpk + (((tap * 16 + c32 * 4 + kg) * 256) + cout0 + cc) * 8;
    *(short8*)dst = *(short8*)ob;
}

// ---------------- K4: conv via bf16 MFMA, 2-row x 128-cout blocks ------------
// grid 256 = b(8) x rowpair(16) x cout-half(2); 512 thr = 8 waves
// = rloc(2) x coutgroup(4). Row-waves of a coutgroup share weight addresses
// (L1 temporal reuse); per-CU weight fetch halves vs 1-row blocks.
__global__ __launch_bounds__(512, 1) void k_conv(
    const void* __restrict__ wsv, float* __restrict__ out) {
    const unsigned short* wp = (const unsigned short*)((const char*)wsv + WS_WP_OFF);
    const char* xe = (const char*)wsv + WS_XE_OFF;
    __shared__ __align__(16) unsigned short ldsx[4 * 34 * 128];   // 34816 B

    int bid = blockIdx.x;
    int ch  = bid & 1;
    int rp  = (bid >> 1) & 15;
    int b   = bid >> 5;
    int h0  = rp * 2;
    int tid = threadIdx.x;

    // staging: padded rows h0..h0+3 = contiguous 34816 B, pre-swizzled.
    const char* src = xe + ((b * 34 + h0) * 34) * 256;
    #pragma unroll 2
    for (int i = tid; i < 2176; i += 512) {
        *(short8*)((char*)ldsx + i * 16) = *(const short8*)(src + i * 16);
    }
    __syncthreads();

    int lane = tid & 63;
    int wave = tid >> 6;
    int rloc = wave >> 2;         // 0..1 row within pair
    int cg   = wave & 3;          // 0..3 cout32 group
    int l15  = lane & 15;
    int kg   = lane >> 4;
    int coutbase = (ch << 7) + cg * 32;

    f32x4 acc[2][2];
    #pragma unroll
    for (int mt = 0; mt < 2; mt++)
        #pragma unroll
        for (int nt = 0; nt < 2; nt++) acc[mt][nt] = (f32x4){0.f, 0.f, 0.f, 0.f};

    // per-lane weight base; tap stride = 32768 ushorts, q stride = 8192,
    // nt stride = 128. rloc 0/1 waves share these addresses.
    const unsigned short* wbase = wp + ((kg * 256) + coutbase + l15) * 8;

    short8 bc[8], bn[8];
    #pragma unroll
    for (int q = 0; q < 4; q++) {
        bc[2 * q]     = *(const short8*)(wbase + q * 8192);
        bc[2 * q + 1] = *(const short8*)(wbase + q * 8192 + 128);
    }

    #pragma unroll
    for (int dh = 0; dh < 3; dh++) {
        #pragma unroll
        for (int dw = 0; dw < 3; dw++) {
            int tap = dh * 3 + dw;
            if (tap < 8) {
                const unsigned short* wnx = wbase + (tap + 1) * 32768;
                #pragma unroll
                for (int q = 0; q < 4; q++) {
                    bn[2 * q]     = *(const short8*)(wnx + q * 8192);
                    bn[2 * q + 1] = *(const short8*)(wnx + q * 8192 + 128);
                }
            }
            int r0  = (rloc + dh) * 34 + l15 + dw;   // LDS row
            int r1  = r0 + 16;                       // +16: same key mod 8
            int key = ((l15 + dw) & 7) << 4;         // pos-keyed swizzle
            #pragma unroll
            for (int q = 0; q < 4; q++) {
                int cbyte = q * 64 + kg * 16;
                short8 a0f8 = *(const short8*)((const char*)ldsx +
                               (r0 * 256 + (cbyte ^ key)));
                short8 a1f8 = *(const short8*)((const char*)ldsx +
                               (r1 * 256 + (cbyte ^ key)));
                acc[0][0] = __builtin_amdgcn_mfma_f32_16x16x32_bf16(a0f8, bc[2*q],   acc[0][0], 0, 0, 0);
                acc[0][1] = __builtin_amdgcn_mfma_f32_16x16x32_bf16(a0f8, bc[2*q+1], acc[0][1], 0, 0, 0);
                acc[1][0] = __builtin_amdgcn_mfma_f32_16x16x32_bf16(a1f8, bc[2*q],   acc[1][0], 0, 0, 0);
                acc[1][1] = __builtin_amdgcn_mfma_f32_16x16x32_bf16(a1f8, bc[2*q+1], acc[1][1], 0, 0, 0);
            }
            if (tap < 8) {
                #pragma unroll
                for (int i = 0; i < 8; i++) bc[i] = bn[i];
            }
        }
    }

    // D: col = lane&15 (cout), row = kg*4 + reg (pos within 16-tile)
    #pragma unroll
    for (int mt = 0; mt < 2; mt++) {
        #pragma unroll
        for (int nt = 0; nt < 2; nt++) {
            int col = coutbase + nt * 16 + l15;
            #pragma unroll
            for (int reg = 0; reg < 4; reg++) {
                int row = mt * 16 + kg * 4 + reg;
                out[(((b * 32 + h0 + rloc) * 32) + row) * 256 + col] = acc[mt][nt][reg];
            }
        }
    }
}

extern "C" void kernel_launch(void* const* d_in, const int* in_sizes, int n_in,
                              void* d_out, int out_size, void* d_ws, size_t ws_size,
                              hipStream_t stream) {
    const float* x      = (const float*)d_in[0];
    const float* w      = (const float*)d_in[1];
    const float* shiftp = (const float*)d_in[2];
    const float* beta   = (const float*)d_in[3];
    const float* a0     = (const float*)d_in[4];
    float* out = (float*)d_out;

    k_pre<<<192, 256, 0, stream>>>(w, x, shiftp, beta, d_ws);
    k_gc<<<NBLK_RED, 256, 0, stream>>>(w, d_ws);
    k_weff<<<144, 256, 0, stream>>>(w, a0, d_ws);
    k_conv<<<256, 512, 0, stream>>>(d_ws, out);
}